// Round 1
// baseline (192.055 us; speedup 1.0000x reference)
//
#include <hip/hip_runtime.h>
#include <math.h>

#define EPS_F 1e-6f
constexpr int B_ = 64, Q_ = 900, N_ = 100, C_ = 256;
constexpr float BOX_W = 5.0f, GIOU_W = 2.0f, CLS_W = 1.0f;

__device__ __forceinline__ float giou_f(float px0, float py0, float px1, float py1, float pa,
                                        float tx0, float ty0, float tx1, float ty1, float ta) {
    float ltx = fmaxf(px0, tx0), lty = fmaxf(py0, ty0);
    float rbx = fminf(px1, tx1), rby = fminf(py1, ty1);
    float w = fmaxf(rbx - ltx, 0.0f), h = fmaxf(rby - lty, 0.0f);
    float inter = w * h;
    float uni = pa + ta - inter;
    float iou = inter / (uni + EPS_F);
    float ex0 = fminf(px0, tx0), ey0 = fminf(py0, ty0);
    float ex1 = fmaxf(px1, tx1), ey1 = fmaxf(py1, ty1);
    float ew = fmaxf(ex1 - ex0, 0.0f), eh = fmaxf(ey1 - ey0, 0.0f);
    float earea = ew * eh;
    return iou - (earea - uni) / (earea + EPS_F);
}

__global__ __launch_bounds__(256) void match_loss_kernel(
    const float* __restrict__ pred_boxes,    // [B,Q,4] cxcywh
    const float* __restrict__ pred_logits,   // [B,Q,C]
    const float* __restrict__ target_boxes,  // [B,N,4] xyxy
    const int*   __restrict__ target_labels, // [B,N]
    double* __restrict__ partial)            // [B]
{
    const int b = blockIdx.x;
    const int tid = threadIdx.x;

    __shared__ float t_x0[N_], t_y0[N_], t_x1[N_], t_y1[N_], t_area[N_];
    __shared__ int   s_lab[N_];
    __shared__ int   s_match[N_];
    __shared__ float s_rv[4];
    __shared__ int   s_ri[4];
    __shared__ double s_red[256];

    // ---- load targets into LDS ----
    if (tid < N_) {
        const float* tb = target_boxes + (size_t)(b * N_ + tid) * 4;
        float x0 = tb[0], y0 = tb[1], x1 = tb[2], y1 = tb[3];
        t_x0[tid] = x0; t_y0[tid] = y0; t_x1[tid] = x1; t_y1[tid] = y1;
        t_area[tid] = (x1 - x0) * (y1 - y0);
        s_lab[tid] = target_labels[b * N_ + tid];
    }

    // ---- load this thread's pred boxes into registers ----
    float px0[4], py0[4], px1[4], py1[4], pa[4];
    bool  valid[4], used[4];
    #pragma unroll
    for (int k = 0; k < 4; ++k) {
        int q = tid + k * 256;
        valid[k] = (q < Q_);
        used[k] = false;
        px0[k] = py0[k] = px1[k] = py1[k] = pa[k] = 0.0f;
        if (valid[k]) {
            const float* pb = pred_boxes + (size_t)(b * Q_ + q) * 4;
            float cx = pb[0], cy = pb[1], w = pb[2], h = pb[3];
            px0[k] = cx - 0.5f * w; py0[k] = cy - 0.5f * h;
            px1[k] = cx + 0.5f * w; py1[k] = cy + 0.5f * h;
            pa[k]  = (px1[k] - px0[k]) * (py1[k] - py0[k]);
        }
    }
    __syncthreads();

    // ---- greedy match: 100 sequential argmax steps ----
    for (int n = 0; n < N_; ++n) {
        float tx0 = t_x0[n], ty0 = t_y0[n], tx1 = t_x1[n], ty1 = t_y1[n], ta = t_area[n];
        float bv = -INFINITY;
        int   bi = 0x7fffffff;
        #pragma unroll
        for (int k = 0; k < 4; ++k) {
            if (valid[k] && !used[k]) {
                float g = giou_f(px0[k], py0[k], px1[k], py1[k], pa[k], tx0, ty0, tx1, ty1, ta);
                int q = tid + k * 256;
                if (g > bv || (g == bv && q < bi)) { bv = g; bi = q; }
            }
        }
        // wave (64-lane) argmax, tie -> min index
        #pragma unroll
        for (int off = 32; off >= 1; off >>= 1) {
            float ov = __shfl_xor(bv, off);
            int   oi = __shfl_xor(bi, off);
            if (ov > bv || (ov == bv && oi < bi)) { bv = ov; bi = oi; }
        }
        int wave = tid >> 6;
        if ((tid & 63) == 0) { s_rv[wave] = bv; s_ri[wave] = bi; }
        __syncthreads();
        float fv = s_rv[0]; int fi = s_ri[0];
        #pragma unroll
        for (int wv = 1; wv < 4; ++wv) {
            float ov = s_rv[wv]; int oi = s_ri[wv];
            if (ov > fv || (ov == fv && oi < fi)) { fv = ov; fi = oi; }
        }
        if (tid == 0) s_match[n] = fi;
        #pragma unroll
        for (int k = 0; k < 4; ++k)
            if (tid + k * 256 == fi) used[k] = true;
        __syncthreads();  // protect s_rv/s_ri for next iter
    }

    // ---- losses ----
    double acc = 0.0;

    // L1 + elementwise GIoU: one target per thread (tid < 100)
    if (tid < N_) {
        int n = tid;
        int q = s_match[n];
        const float* pb = pred_boxes + (size_t)(b * Q_ + q) * 4;
        float cx = pb[0], cy = pb[1], w = pb[2], h = pb[3];
        float tx0 = t_x0[n], ty0 = t_y0[n], tx1 = t_x1[n], ty1 = t_y1[n];
        // target cxcywh
        float tcx = (tx0 + tx1) * 0.5f, tcy = (ty0 + ty1) * 0.5f;
        float tw = tx1 - tx0, th = ty1 - ty0;
        float l1 = fabsf(cx - tcx) + fabsf(cy - tcy) + fabsf(w - tw) + fabsf(h - th);
        // pred xyxy
        float qx0 = cx - 0.5f * w, qy0 = cy - 0.5f * h;
        float qx1 = cx + 0.5f * w, qy1 = cy + 0.5f * h;
        float qa = (qx1 - qx0) * (qy1 - qy0);
        float g = giou_f(qx0, qy0, qx1, qy1, qa, tx0, ty0, tx1, ty1, t_area[n]);
        acc += (double)(BOX_W * l1) + (double)(GIOU_W * (1.0f - g));
    }

    // BCE over gathered logit rows: thread = class index, loop over targets
    for (int n = 0; n < N_; ++n) {
        int q = s_match[n];
        int lab = s_lab[n];
        float x = pred_logits[((size_t)(b * Q_ + q)) * C_ + tid];
        float t = (tid == lab) ? 1.0f : 0.0f;
        float term = fmaxf(x, 0.0f) - x * t + log1pf(expf(-fabsf(x)));
        acc += (double)(CLS_W * term);
    }

    // block reduce (deterministic tree)
    s_red[tid] = acc;
    __syncthreads();
    #pragma unroll
    for (int s = 128; s >= 1; s >>= 1) {
        if (tid < s) s_red[tid] += s_red[tid + s];
        __syncthreads();
    }
    if (tid == 0) partial[b] = s_red[0];
}

__global__ void finalize_kernel(const double* __restrict__ partial, float* __restrict__ out) {
    if (threadIdx.x == 0 && blockIdx.x == 0) {
        double s = 0.0;
        for (int i = 0; i < B_; ++i) s += partial[i];
        out[0] = (float)(s / (double)(B_ * N_));
    }
}

extern "C" void kernel_launch(void* const* d_in, const int* in_sizes, int n_in,
                              void* d_out, int out_size, void* d_ws, size_t ws_size,
                              hipStream_t stream) {
    const float* pred_boxes    = (const float*)d_in[0];
    const float* pred_logits   = (const float*)d_in[1];
    const float* target_boxes  = (const float*)d_in[2];
    const int*   target_labels = (const int*)d_in[3];
    float* out = (float*)d_out;
    double* partial = (double*)d_ws;  // 64 doubles = 512 B

    hipLaunchKernelGGL(match_loss_kernel, dim3(B_), dim3(256), 0, stream,
                       pred_boxes, pred_logits, target_boxes, target_labels, partial);
    hipLaunchKernelGGL(finalize_kernel, dim3(1), dim3(64), 0, stream, partial, out);
}

// Round 2
// 66.730 us; speedup vs baseline: 2.8781x; 2.8781x over previous
//
#include <hip/hip_runtime.h>
#include <math.h>

constexpr int B_ = 64, Q_ = 900, N_ = 100, C_ = 256;
constexpr float EPSF = 1e-6f;
constexpr float BOX_W = 5.0f, GIOU_W = 2.0f, CLS_W = 1.0f;
constexpr int KP = 15;  // preds per lane: 64 lanes * 15 >= 900

__device__ __forceinline__ float giou_f(float px0, float py0, float px1, float py1, float pa,
                                        float tx0, float ty0, float tx1, float ty1, float ta) {
    float ltx = fmaxf(px0, tx0), lty = fmaxf(py0, ty0);
    float rbx = fminf(px1, tx1), rby = fminf(py1, ty1);
    float w = fmaxf(rbx - ltx, 0.0f), h = fmaxf(rby - lty, 0.0f);
    float inter = w * h;
    float uni = pa + ta - inter;
    float iou = inter / (uni + EPSF);
    float ex0 = fminf(px0, tx0), ey0 = fminf(py0, ty0);
    float ex1 = fmaxf(px1, tx1), ey1 = fmaxf(py1, ty1);
    float ew = fmaxf(ex1 - ex0, 0.0f), eh = fmaxf(ey1 - ey0, 0.0f);
    float earea = ew * eh;
    return iou - (earea - uni) / (earea + EPSF);
}

// order-preserving float->uint, then key = (ord << 32) | ~q  => u64 max == (max value, min index)
__device__ __forceinline__ unsigned int f2ord(float f) {
    unsigned int u = __float_as_uint(f);
    return (u & 0x80000000u) ? ~u : (u | 0x80000000u);
}
__device__ __forceinline__ unsigned long long mkkey(float g, int q) {
    return ((unsigned long long)f2ord(g) << 32) | (unsigned int)(~(unsigned int)q);
}

// ---------------- kernel 1: per-column unconstrained top-2 ----------------
__global__ __launch_bounds__(64) void cand_kernel(
    const float* __restrict__ pred_boxes,   // [B,Q,4] cxcywh
    const float* __restrict__ target_boxes, // [B,N,4] xyxy
    unsigned long long* __restrict__ c1,    // [B*N]
    unsigned long long* __restrict__ c2)    // [B*N]
{
    const int bn = blockIdx.x;
    const int b = bn / N_;
    const int lane = threadIdx.x;

    const float* t = target_boxes + (size_t)bn * 4;
    float tx0 = t[0], ty0 = t[1], tx1 = t[2], ty1 = t[3];
    float ta = (tx1 - tx0) * (ty1 - ty0);

    const float4* pbv = (const float4*)(pred_boxes + (size_t)b * Q_ * 4);
    unsigned long long k1 = 0ull, k2 = 0ull;
    #pragma unroll
    for (int k = 0; k < KP; ++k) {
        int q = lane + (k << 6);
        if (q < Q_) {
            float4 c = pbv[q];
            float x0 = c.x - 0.5f * c.z, y0 = c.y - 0.5f * c.w;
            float x1 = c.x + 0.5f * c.z, y1 = c.y + 0.5f * c.w;
            float pa = (x1 - x0) * (y1 - y0);
            float g = giou_f(x0, y0, x1, y1, pa, tx0, ty0, tx1, ty1, ta);
            unsigned long long kk = mkkey(g, q);
            if (kk > k1) { k2 = k1; k1 = kk; }
            else if (kk > k2) { k2 = kk; }
        }
    }
    #pragma unroll
    for (int off = 32; off >= 1; off >>= 1) {
        unsigned long long o1 = __shfl_xor(k1, off);
        unsigned long long o2 = __shfl_xor(k2, off);
        unsigned long long n1 = (k1 > o1) ? k1 : o1;
        unsigned long long mn = (k1 > o1) ? o1 : k1;
        unsigned long long mx2 = (k2 > o2) ? k2 : o2;
        unsigned long long n2 = (mn > mx2) ? mn : mx2;
        k1 = n1; k2 = n2;
    }
    if (lane == 0) { c1[bn] = k1; c2[bn] = k2; }
}

// ---------------- kernel 2: sequential greedy resolve + box losses ----------------
__global__ __launch_bounds__(64) void match_kernel(
    const float* __restrict__ pred_boxes,
    const float* __restrict__ target_boxes,
    const unsigned long long* __restrict__ c1g,
    const unsigned long long* __restrict__ c2g,
    int* __restrict__ matches,   // [B*N]
    double* __restrict__ box_part)
{
    const int b = blockIdx.x;
    const int lane = threadIdx.x;

    __shared__ float tx0s[N_], ty0s[N_], tx1s[N_], ty1s[N_], tas[N_];
    __shared__ unsigned long long c1s[N_], c2s[N_];
    __shared__ unsigned int usedw[32];
    __shared__ int ms[N_];

    for (int n = lane; n < N_; n += 64) {
        const float* t = target_boxes + (size_t)(b * N_ + n) * 4;
        float x0 = t[0], y0 = t[1], x1 = t[2], y1 = t[3];
        tx0s[n] = x0; ty0s[n] = y0; tx1s[n] = x1; ty1s[n] = y1;
        tas[n] = (x1 - x0) * (y1 - y0);
        c1s[n] = c1g[b * N_ + n];
        c2s[n] = c2g[b * N_ + n];
    }
    if (lane < 32) usedw[lane] = 0u;

    // this lane's pred boxes in registers
    float px0[KP], py0[KP], px1[KP], py1[KP], pa[KP];
    const float4* pbv = (const float4*)(pred_boxes + (size_t)b * Q_ * 4);
    #pragma unroll
    for (int k = 0; k < KP; ++k) {
        int q = lane + (k << 6);
        px0[k] = py0[k] = px1[k] = py1[k] = pa[k] = 0.0f;
        if (q < Q_) {
            float4 c = pbv[q];
            px0[k] = c.x - 0.5f * c.z; py0[k] = c.y - 0.5f * c.w;
            px1[k] = c.x + 0.5f * c.z; py1[k] = c.y + 0.5f * c.w;
            pa[k] = (px1[k] - px0[k]) * (py1[k] - py0[k]);
        }
    }
    unsigned int um = 0;  // used bits for my KP preds
    __syncthreads();

    for (int n = 0; n < N_; ++n) {
        unsigned long long k1 = c1s[n];
        int i1 = (int)(~(unsigned int)k1);
        int win;
        if (!((usedw[i1 >> 5] >> (i1 & 31)) & 1u)) {
            win = i1;
        } else {
            unsigned long long k2 = c2s[n];
            int i2 = (int)(~(unsigned int)k2);
            if (!((usedw[i2 >> 5] >> (i2 & 31)) & 1u)) {
                win = i2;
            } else {
                // rare: full masked argmax
                float tx0 = tx0s[n], ty0 = ty0s[n], tx1 = tx1s[n], ty1 = ty1s[n], ta = tas[n];
                unsigned long long bk = 0ull;
                #pragma unroll
                for (int k = 0; k < KP; ++k) {
                    int q = lane + (k << 6);
                    if (q < Q_ && !((um >> k) & 1u)) {
                        float g = giou_f(px0[k], py0[k], px1[k], py1[k], pa[k],
                                         tx0, ty0, tx1, ty1, ta);
                        unsigned long long kk = mkkey(g, q);
                        if (kk > bk) bk = kk;
                    }
                }
                #pragma unroll
                for (int off = 32; off >= 1; off >>= 1) {
                    unsigned long long o = __shfl_xor(bk, off);
                    if (o > bk) bk = o;
                }
                win = (int)(~(unsigned int)bk);
            }
        }
        if (lane == (win & 63)) {
            usedw[win >> 5] |= (1u << (win & 31));
            um |= (1u << (win >> 6));
            ms[n] = win;
        }
        __syncthreads();
    }

    // box losses: L1 + GIoU on matched pairs
    double acc = 0.0;
    for (int n = lane; n < N_; n += 64) {
        int q = ms[n];
        matches[b * N_ + n] = q;
        float4 c = pbv[q];
        float tx0 = tx0s[n], ty0 = ty0s[n], tx1 = tx1s[n], ty1 = ty1s[n];
        float tcx = (tx0 + tx1) * 0.5f, tcy = (ty0 + ty1) * 0.5f;
        float tw = tx1 - tx0, th = ty1 - ty0;
        float l1 = fabsf(c.x - tcx) + fabsf(c.y - tcy) + fabsf(c.z - tw) + fabsf(c.w - th);
        float x0 = c.x - 0.5f * c.z, y0 = c.y - 0.5f * c.w;
        float x1 = c.x + 0.5f * c.z, y1 = c.y + 0.5f * c.w;
        float pa = (x1 - x0) * (y1 - y0);
        float g = giou_f(x0, y0, x1, y1, pa, tx0, ty0, tx1, ty1, tas[n]);
        acc += (double)(BOX_W * l1) + (double)(GIOU_W * (1.0f - g));
    }
    #pragma unroll
    for (int off = 32; off >= 1; off >>= 1) acc += __shfl_xor(acc, off);
    if (lane == 0) box_part[b] = acc;
}

// ---------------- kernel 3: BCE over gathered logit rows ----------------
__global__ __launch_bounds__(64) void bce_kernel(
    const float* __restrict__ pred_logits,   // [B,Q,C]
    const int* __restrict__ target_labels,   // [B,N]
    const int* __restrict__ matches,         // [B*N]
    double* __restrict__ part)               // [B*N]
{
    const int bn = blockIdx.x;
    const int b = bn / N_;
    const int lane = threadIdx.x;
    const int q = matches[bn];
    const int lab = target_labels[bn];

    const float4* row = (const float4*)(pred_logits + ((size_t)(b * Q_ + q)) * C_);
    float4 v = row[lane];
    int base = lane * 4;
    float xs[4] = {v.x, v.y, v.z, v.w};
    double acc = 0.0;
    #pragma unroll
    for (int j = 0; j < 4; ++j) {
        float x = xs[j];
        float t = (base + j == lab) ? 1.0f : 0.0f;
        float term = fmaxf(x, 0.0f) - x * t + log1pf(expf(-fabsf(x)));
        acc += (double)term;
    }
    #pragma unroll
    for (int off = 32; off >= 1; off >>= 1) acc += __shfl_xor(acc, off);
    if (lane == 0) part[bn] = acc * (double)CLS_W;
}

// ---------------- kernel 4: final reduce ----------------
__global__ __launch_bounds__(256) void finalize_kernel(
    const double* __restrict__ bce_part,  // [B*N]
    const double* __restrict__ box_part,  // [B]
    float* __restrict__ out)
{
    const int tid = threadIdx.x;
    double acc = 0.0;
    for (int i = tid; i < B_ * N_; i += 256) acc += bce_part[i];
    if (tid < B_) acc += box_part[tid];
    __shared__ double red[256];
    red[tid] = acc;
    __syncthreads();
    #pragma unroll
    for (int s = 128; s >= 1; s >>= 1) {
        if (tid < s) red[tid] += red[tid + s];
        __syncthreads();
    }
    if (tid == 0) out[0] = (float)(red[0] / (double)(B_ * N_));
}

extern "C" void kernel_launch(void* const* d_in, const int* in_sizes, int n_in,
                              void* d_out, int out_size, void* d_ws, size_t ws_size,
                              hipStream_t stream) {
    const float* pred_boxes    = (const float*)d_in[0];
    const float* pred_logits   = (const float*)d_in[1];
    const float* target_boxes  = (const float*)d_in[2];
    const int*   target_labels = (const int*)d_in[3];
    float* out = (float*)d_out;

    char* ws = (char*)d_ws;
    unsigned long long* c1 = (unsigned long long*)(ws);              // 6400*8
    unsigned long long* c2 = (unsigned long long*)(ws + 51200);      // 6400*8
    int*    matches  = (int*)(ws + 102400);                          // 6400*4
    double* bce_part = (double*)(ws + 128000);                       // 6400*8
    double* box_part = (double*)(ws + 179200);                       // 64*8

    hipLaunchKernelGGL(cand_kernel, dim3(B_ * N_), dim3(64), 0, stream,
                       pred_boxes, target_boxes, c1, c2);
    hipLaunchKernelGGL(match_kernel, dim3(B_), dim3(64), 0, stream,
                       pred_boxes, target_boxes, c1, c2, matches, box_part);
    hipLaunchKernelGGL(bce_kernel, dim3(B_ * N_), dim3(64), 0, stream,
                       pred_logits, target_labels, matches, bce_part);
    hipLaunchKernelGGL(finalize_kernel, dim3(1), dim3(256), 0, stream,
                       bce_part, box_part, out);
}